// Round 2
// baseline (278.706 us; speedup 1.0000x reference)
//
#include <hip/hip_runtime.h>
#include <hip/hip_bf16.h>

typedef short bf8 __attribute__((ext_vector_type(8)));   // 8 bf16 values (4 VGPRs)
typedef float f4 __attribute__((ext_vector_type(4)));

#define S_LEN 4096
#define H_DIM 1024
#define D_DIM 512
#define B_DIM 16
#define BK 64
#define PAD 8
#define LDA (BK + PAD)

// float -> bf16 bits with round-to-nearest-even
static __device__ __forceinline__ unsigned short f2bf(float f) {
    union { float f; unsigned int u; } c; c.f = f;
    unsigned int u = c.u;
    unsigned int r = (u + 0x7FFFu + ((u >> 16) & 1u)) >> 16;
    return (unsigned short)r;
}

// cW1 [K=1024][N=512] f32 row-major  ->  wT [N=512][K=1024] bf16
__global__ __launch_bounds__(256) void prep_transpose(const float* __restrict__ cW1,
                                                      unsigned short* __restrict__ wT) {
    __shared__ float tile[64][68];
    const int kt = blockIdx.x >> 3;   // 16 k-tiles of 64
    const int nt = blockIdx.x & 7;    // 8 n-tiles of 64
    const int tr = threadIdx.x >> 4;  // 0..15
    const int tc = threadIdx.x & 15;  // 0..15
#pragma unroll
    for (int i = 0; i < 4; ++i) {
        const float4 v = *(const float4*)(cW1 + (size_t)(kt * 64 + i * 16 + tr) * D_DIM + nt * 64 + tc * 4);
        tile[i * 16 + tr][tc * 4 + 0] = v.x;
        tile[i * 16 + tr][tc * 4 + 1] = v.y;
        tile[i * 16 + tr][tc * 4 + 2] = v.z;
        tile[i * 16 + tr][tc * 4 + 3] = v.w;
    }
    __syncthreads();
#pragma unroll
    for (int i = 0; i < 4; ++i) {
        const int n = i * 16 + tr;
        ushort4 o;
        o.x = f2bf(tile[tc * 4 + 0][n]);
        o.y = f2bf(tile[tc * 4 + 1][n]);
        o.z = f2bf(tile[tc * 4 + 2][n]);
        o.w = f2bf(tile[tc * 4 + 3][n]);
        *(ushort4*)(wT + (size_t)(nt * 64 + n) * H_DIM + kt * 64 + tc * 4) = o;
    }
}

// steps_used ≡ 1 (structurally guaranteed: rb<=128-t can never make trunc(rb/(S-t+1))>=2,
// and negative rb clips to MIN_STEPS=1), rb_final = 128 - 4096 = -3968.
__global__ __launch_bounds__(256) void write_consts(float* __restrict__ out) {
    const size_t steps_off = (size_t)B_DIM * S_LEN * H_DIM;
    const int i = blockIdx.x * 256 + threadIdx.x;
    if (i < S_LEN) out[steps_off + i] = 1.0f;
    if (i == 0) out[steps_off + 2 * S_LEN] = -3968.0f;
}

// Fused: states copy -> d_out  +  comp_mean[s] = mean_b sigmoid(relu(states@cW1+cb1)@cW2+cb2)
// Block tile: 64 rows (4 s x 16 b) x full N=512, K-loop BK=64, A double-buffered in LDS,
// B fragments read directly from L2-resident wT. 8 waves = 1(M) x 8(N), wave tile 64x64.
__global__ __launch_bounds__(512, 4) void fused_gemm_kernel(
    const float* __restrict__ states,
    const unsigned short* __restrict__ wT,
    const float* __restrict__ cb1,
    const float* __restrict__ cW2,
    const float* __restrict__ cb2,
    float* __restrict__ out) {
    __shared__ unsigned short As[2][64][LDA];   // 18.4 KB
    __shared__ float part[4][16][8];            // 2 KB

    const int t = threadIdx.x;
    const int lane = t & 63;
    const int w = t >> 6;        // 0..7 : wave col slice [w*64, w*64+64)
    const int la = lane & 15;
    const int lg = lane >> 4;
    const int s0 = blockIdx.x * 4;

    // ---- staging mapping: 512 threads x 8 floats = 64 rows x 64 k per chunk ----
    const int r = t >> 3;        // tile row 0..63 (r = jj*16 + bb)
    const int ks = t & 7;
    const int bb = r & 15;
    const int jj = r >> 4;
    const size_t grow = ((size_t)bb * S_LEN + s0 + jj) * H_DIM + ks * 8;
    const float* sp = states + grow;
    float* op = out + grow;
    unsigned short* aw = &As[0][r][ks * 8];          // + buf*64*LDA for buffer 1
    const unsigned short* bp = wT + (size_t)(w * 64 + la) * H_DIM + lg * 8;

    f4 acc[4][4];
#pragma unroll
    for (int a = 0; a < 4; ++a)
#pragma unroll
        for (int b = 0; b < 4; ++b) acc[a][b] = f4{0.f, 0.f, 0.f, 0.f};

    // ---- prologue: stage chunk 0 ----
    {
        const float4 p0 = *(const float4*)sp;
        const float4 p1 = *(const float4*)(sp + 4);
        *(float4*)op = p0;
        *(float4*)(op + 4) = p1;
        bf8 av;
        av[0] = (short)f2bf(p0.x); av[1] = (short)f2bf(p0.y);
        av[2] = (short)f2bf(p0.z); av[3] = (short)f2bf(p0.w);
        av[4] = (short)f2bf(p1.x); av[5] = (short)f2bf(p1.y);
        av[6] = (short)f2bf(p1.z); av[7] = (short)f2bf(p1.w);
        *(bf8*)aw = av;
    }
    __syncthreads();

    int cur = 0;
    for (int ck = 0; ck < 16; ++ck) {
        const int k0 = ck * BK;
        // ---- issue next chunk's global loads early (latency hides under MFMA) ----
        float4 q0, q1;
        if (ck < 15) {
            q0 = *(const float4*)(sp + (ck + 1) * BK);
            q1 = *(const float4*)(sp + (ck + 1) * BK + 4);
        }
        // ---- compute on As[cur]; B fragments straight from L2 ----
#pragma unroll
        for (int kk = 0; kk < 2; ++kk) {
            bf8 b4[4];
#pragma unroll
            for (int fc = 0; fc < 4; ++fc)
                b4[fc] = *(const bf8*)(bp + (size_t)fc * 16 * H_DIM + k0 + kk * 32);
            bf8 af[4];
#pragma unroll
            for (int fr = 0; fr < 4; ++fr)
                af[fr] = *(const bf8*)&As[cur][fr * 16 + la][kk * 32 + lg * 8];
#pragma unroll
            for (int fr = 0; fr < 4; ++fr)
#pragma unroll
                for (int fc = 0; fc < 4; ++fc)
                    acc[fr][fc] = __builtin_amdgcn_mfma_f32_16x16x32_bf16(af[fr], b4[fc], acc[fr][fc], 0, 0, 0);
        }
        // ---- write-late: out copy + bf16 pack + ds_write to other buffer ----
        if (ck < 15) {
            *(float4*)(op + (ck + 1) * BK) = q0;
            *(float4*)(op + (ck + 1) * BK + 4) = q1;
            bf8 av;
            av[0] = (short)f2bf(q0.x); av[1] = (short)f2bf(q0.y);
            av[2] = (short)f2bf(q0.z); av[3] = (short)f2bf(q0.w);
            av[4] = (short)f2bf(q1.x); av[5] = (short)f2bf(q1.y);
            av[6] = (short)f2bf(q1.z); av[7] = (short)f2bf(q1.w);
            *(bf8*)(aw + (cur ^ 1) * 64 * LDA) = av;
        }
        __syncthreads();
        cur ^= 1;
    }

    // ---- epilogue: relu + dot(cW2) + sigmoid + mean over b ----
    float w2v[4], b1v[4];
#pragma unroll
    for (int fc = 0; fc < 4; ++fc) {
        const int d = w * 64 + fc * 16 + la;
        w2v[fc] = cW2[d];
        b1v[fc] = cb1[d];
    }
#pragma unroll
    for (int fr = 0; fr < 4; ++fr) {       // fr == s-offset j
#pragma unroll
        for (int rg = 0; rg < 4; ++rg) {
            float p = 0.f;
#pragma unroll
            for (int fc = 0; fc < 4; ++fc) {
                const float h = acc[fr][fc][rg] + b1v[fc];
                p += fmaxf(h, 0.f) * w2v[fc];
            }
#pragma unroll
            for (int off = 1; off < 16; off <<= 1)
                p += __shfl_xor(p, off, 64);   // sum over 16 lane-columns
            if (la == 0) part[fr][lg * 4 + rg][w] = p;
        }
    }
    __syncthreads();
    if (t < 64) {
        const int j = t >> 4;   // s offset 0..3
        const int b = t & 15;
        float sum = cb2[0];
#pragma unroll
        for (int ww = 0; ww < 8; ++ww) sum += part[j][b][ww];
        float sg = 1.f / (1.f + __expf(-sum));
#pragma unroll
        for (int off = 1; off < 16; off <<= 1)
            sg += __shfl_xor(sg, off, 64);  // mean over b
        if (b == 0)
            out[(size_t)B_DIM * S_LEN * H_DIM + S_LEN + s0 + j] = sg * (1.f / 16.f);
    }
}

extern "C" void kernel_launch(void* const* d_in, const int* in_sizes, int n_in,
                              void* d_out, int out_size, void* d_ws, size_t ws_size,
                              hipStream_t stream) {
    const float* states = (const float*)d_in[0];
    const float* cW1 = (const float*)d_in[5];
    const float* cb1 = (const float*)d_in[6];
    const float* cW2 = (const float*)d_in[7];
    const float* cb2 = (const float*)d_in[8];
    float* out = (float*)d_out;
    unsigned short* wT = (unsigned short*)d_ws;  // 512*1024 bf16 = 1 MB

    hipLaunchKernelGGL(prep_transpose, dim3(128), dim3(256), 0, stream, cW1, wT);
    hipLaunchKernelGGL(write_consts, dim3(16), dim3(256), 0, stream, out);
    hipLaunchKernelGGL(fused_gemm_kernel, dim3(1024), dim3(512), 0, stream,
                       states, wT, cb1, cW2, cb2, out);
}

// Round 3
// 224.539 us; speedup vs baseline: 1.2412x; 1.2412x over previous
//
#include <hip/hip_runtime.h>
#include <hip/hip_bf16.h>

typedef short bf8 __attribute__((ext_vector_type(8)));   // 8 bf16 (4 VGPRs)
typedef float f4 __attribute__((ext_vector_type(4)));
typedef unsigned int u32;
typedef const __attribute__((address_space(1))) void* gvp;
typedef __attribute__((address_space(3))) void* lvp;

#define S_LEN 4096
#define H_DIM 1024
#define D_DIM 512
#define B_DIM 16

// float -> bf16 bits, round-to-nearest-even
static __device__ __forceinline__ unsigned short f2bf(float f) {
    union { float f; unsigned int u; } c; c.f = f;
    unsigned int u = c.u;
    return (unsigned short)((u + 0x7FFFu + ((u >> 16) & 1u)) >> 16);
}

// cW1 [K=1024][N=512] f32 row-major  ->  wT [N=512][K=1024] bf16
__global__ __launch_bounds__(256) void prep_transpose(const float* __restrict__ cW1,
                                                      unsigned short* __restrict__ wT) {
    __shared__ float tile[64][68];
    const int kt = blockIdx.x >> 3;
    const int nt = blockIdx.x & 7;
    const int tr = threadIdx.x >> 4;
    const int tc = threadIdx.x & 15;
#pragma unroll
    for (int i = 0; i < 4; ++i) {
        const float4 v = *(const float4*)(cW1 + (size_t)(kt * 64 + i * 16 + tr) * D_DIM + nt * 64 + tc * 4);
        tile[i * 16 + tr][tc * 4 + 0] = v.x;
        tile[i * 16 + tr][tc * 4 + 1] = v.y;
        tile[i * 16 + tr][tc * 4 + 2] = v.z;
        tile[i * 16 + tr][tc * 4 + 3] = v.w;
    }
    __syncthreads();
#pragma unroll
    for (int i = 0; i < 4; ++i) {
        const int n = i * 16 + tr;
        ushort4 o;
        o.x = f2bf(tile[tc * 4 + 0][n]);
        o.y = f2bf(tile[tc * 4 + 1][n]);
        o.z = f2bf(tile[tc * 4 + 2][n]);
        o.w = f2bf(tile[tc * 4 + 3][n]);
        *(ushort4*)(wT + (size_t)(nt * 64 + n) * H_DIM + kt * 64 + tc * 4) = o;
    }
}

// steps_used ≡ 1 (rb<=128-t can never make trunc(rb/(S-t+1))>=2; negative rb clips to 1),
// rb_final = 128 - 4096 = -3968.
__global__ __launch_bounds__(256) void write_consts(float* __restrict__ out) {
    const size_t steps_off = (size_t)B_DIM * S_LEN * H_DIM;
    const int i = blockIdx.x * 256 + threadIdx.x;
    if (i < S_LEN) out[steps_off + i] = 1.0f;
    if (i == 0) out[steps_off + 2 * S_LEN] = -3968.0f;
}

// HBM-bound fused stream: states copy -> d_out + comp_mean.
// Tile 64 rows (4 s x 16 b) x N=512, BK=64 (16 chunks). A: reg-staged depth-2, double-buffered
// LDS. B: single-buffered LDS via global_load_lds(16B), pre-swizzled per-lane source.
// XOR swizzle (slot ^= row&7) on both A and B for conflict-free ds_read_b128.
__global__ __launch_bounds__(512, 4) void fused_gemm_kernel(
    const float* __restrict__ states,
    const unsigned short* __restrict__ wT,
    const float* __restrict__ cb1,
    const float* __restrict__ cW2,
    const float* __restrict__ cb2,
    float* __restrict__ out) {
    __shared__ unsigned short As[2][64][64];   // 16 KB, swizzled
    __shared__ unsigned short Bs[512][64];     // 64 KB, swizzled; total 80 KB -> 2 blocks/CU

    const int t = threadIdx.x;
    const int lane = t & 63;
    const int wv = t >> 6;        // 0..7 : wave col slice [wv*64, +64)
    const int la = lane & 15;
    const int lg = lane >> 4;
    const int s0 = blockIdx.x * 4;

    unsigned short* AsF = &As[0][0][0];
    unsigned short* BsF = &Bs[0][0];

    // ---- A staging map: 2 passes x 512 threads x float4 = 64 rows x 64 k ----
    const int quad = t & 15;
    const int row0 = t >> 4;       // 0..31
    const int row1 = row0 + 32;    // 32..63
    const size_t g0 = ((size_t)(row0 & 15) * S_LEN + s0 + (row0 >> 4)) * H_DIM + quad * 4;
    const size_t g1 = ((size_t)(row1 & 15) * S_LEN + s0 + (row1 >> 4)) * H_DIM + quad * 4;
    const int lw0 = row0 * 64 + (((quad >> 1) ^ (row0 & 7)) * 8) + (quad & 1) * 4;
    const int lw1 = row1 * 64 + (((quad >> 1) ^ (row1 & 7)) * 8) + (quad & 1) * 4;

    // ---- B staging map: 8 global_load_lds(1KB) per wave per chunk ----
    const int rowB = wv * 8 + (lane >> 3);              // + i*64
    const int srcslot = (lane & 7) ^ (lane >> 3);       // pre-swizzled source slot
    const unsigned short* bsrc = wT + (size_t)rowB * H_DIM + srcslot * 8;

    f4 acc[4][4];
#pragma unroll
    for (int a = 0; a < 4; ++a)
#pragma unroll
        for (int b = 0; b < 4; ++b) acc[a][b] = f4{0.f, 0.f, 0.f, 0.f};

    auto issueB = [&](int ck) {
#pragma unroll
        for (int i = 0; i < 8; ++i) {
            __builtin_amdgcn_global_load_lds(
                (gvp)(bsrc + (size_t)i * 64 * H_DIM + ck * 64),
                (lvp)(BsF + (i * 8 + wv) * 512),
                16, 0, 0);
        }
    };

    auto writeA = [&](int nb, int ck, const float4 a0, const float4 a1) {
        *(float4*)(out + g0 + ck * 64) = a0;     // fused states copy-out
        *(float4*)(out + g1 + ck * 64) = a1;
        ushort4 p0; p0.x = f2bf(a0.x); p0.y = f2bf(a0.y); p0.z = f2bf(a0.z); p0.w = f2bf(a0.w);
        ushort4 p1; p1.x = f2bf(a1.x); p1.y = f2bf(a1.y); p1.z = f2bf(a1.z); p1.w = f2bf(a1.w);
        *(ushort4*)(AsF + nb * 4096 + lw0) = p0;
        *(ushort4*)(AsF + nb * 4096 + lw1) = p1;
    };

    auto compute = [&](int cb) {
#pragma unroll
        for (int kk = 0; kk < 2; ++kk) {
            const int sb = ((kk * 4 + lg) ^ (la & 7)) * 8;  // swizzled k-slot (row&7 == la&7)
            bf8 bfv[4], af[4];
#pragma unroll
            for (int fc = 0; fc < 4; ++fc)
                bfv[fc] = *(const bf8*)(BsF + (wv * 64 + fc * 16 + la) * 64 + sb);
#pragma unroll
            for (int fr = 0; fr < 4; ++fr)
                af[fr] = *(const bf8*)(AsF + cb * 4096 + (fr * 16 + la) * 64 + sb);
#pragma unroll
            for (int fr = 0; fr < 4; ++fr)
#pragma unroll
                for (int fc = 0; fc < 4; ++fc)
                    acc[fr][fc] = __builtin_amdgcn_mfma_f32_16x16x32_bf16(af[fr], bfv[fc], acc[fr][fc], 0, 0, 0);
        }
    };

    // ---- prologue: stage chunk 0, prefetch chunk 1 ----
    float4 qA = *(const float4*)(states + g0);
    float4 qB = *(const float4*)(states + g1);
    writeA(0, 0, qA, qB);
    issueB(0);
    qA = *(const float4*)(states + g0 + 64);
    qB = *(const float4*)(states + g1 + 64);
    __syncthreads();

    int cur = 0;
    for (int ck = 0; ck < 16; ++ck) {
        compute(cur);
        __syncthreads();             // all reads of Bs / As[cur] done
        if (ck < 15) {
            float4 nA = qA, nB = qB;
            if (ck < 14) {           // issue chunk ck+2 loads early (~1 chunk of slack)
                nA = *(const float4*)(states + g0 + (ck + 2) * 64);
                nB = *(const float4*)(states + g1 + (ck + 2) * 64);
            }
            writeA(cur ^ 1, ck + 1, qA, qB);   // copy-out + pack + ds_write
            issueB(ck + 1);                    // overwrite Bs (safe: post-barrier)
            qA = nA; qB = nB;
            __syncthreads();         // drains ds_writes + B gload_lds
            cur ^= 1;
        }
    }

    // ---- epilogue: relu + dot(cW2) + sigmoid + mean over b ----
    float w2v[4], b1v[4];
#pragma unroll
    for (int fc = 0; fc < 4; ++fc) {
        const int d = wv * 64 + fc * 16 + la;
        w2v[fc] = cW2[d];
        b1v[fc] = cb1[d];
    }
    float (*part)[16][8] = (float (*)[16][8])AsF;  // overlay on As[0] (last compute read As[1])
#pragma unroll
    for (int fr = 0; fr < 4; ++fr) {     // fr == s-offset j
#pragma unroll
        for (int rg = 0; rg < 4; ++rg) {
            float p = 0.f;
#pragma unroll
            for (int fc = 0; fc < 4; ++fc)
                p += fmaxf(acc[fr][fc][rg] + b1v[fc], 0.f) * w2v[fc];
#pragma unroll
            for (int off = 1; off < 16; off <<= 1)
                p += __shfl_xor(p, off, 64);   // sum over 16 lane-columns
            if (la == 0) part[fr][lg * 4 + rg][wv] = p;
        }
    }
    __syncthreads();
    if (t < 64) {
        const int j = t >> 4;   // s offset 0..3
        const int b = t & 15;
        float sum = cb2[0];
#pragma unroll
        for (int ww = 0; ww < 8; ++ww) sum += part[j][b][ww];
        float sg = 1.f / (1.f + __expf(-sum));
#pragma unroll
        for (int off = 1; off < 16; off <<= 1)
            sg += __shfl_xor(sg, off, 64);  // mean over b
        if (b == 0)
            out[(size_t)B_DIM * S_LEN * H_DIM + S_LEN + s0 + j] = sg * (1.f / 16.f);
    }
}

extern "C" void kernel_launch(void* const* d_in, const int* in_sizes, int n_in,
                              void* d_out, int out_size, void* d_ws, size_t ws_size,
                              hipStream_t stream) {
    const float* states = (const float*)d_in[0];
    const float* cW1 = (const float*)d_in[5];
    const float* cb1 = (const float*)d_in[6];
    const float* cW2 = (const float*)d_in[7];
    const float* cb2 = (const float*)d_in[8];
    float* out = (float*)d_out;
    unsigned short* wT = (unsigned short*)d_ws;  // 512x1024 bf16 = 1 MB

    hipLaunchKernelGGL(prep_transpose, dim3(128), dim3(256), 0, stream, cW1, wT);
    hipLaunchKernelGGL(write_consts, dim3(16), dim3(256), 0, stream, out);
    hipLaunchKernelGGL(fused_gemm_kernel, dim3(1024), dim3(512), 0, stream,
                       states, wT, cb1, cW2, cb2, out);
}

// Round 5
// 221.040 us; speedup vs baseline: 1.2609x; 1.0158x over previous
//
#include <hip/hip_runtime.h>
#include <hip/hip_bf16.h>

typedef short bf8 __attribute__((ext_vector_type(8)));   // 8 bf16 (4 VGPRs)
typedef float f4 __attribute__((ext_vector_type(4)));
typedef const __attribute__((address_space(1))) void* gvp;
typedef __attribute__((address_space(3))) void* lvp;

#define S_LEN 4096
#define H_DIM 1024
#define D_DIM 512
#define B_DIM 16

// float -> bf16 bits, round-to-nearest-even
static __device__ __forceinline__ unsigned short f2bf(float f) {
    union { float f; unsigned int u; } c; c.f = f;
    unsigned int u = c.u;
    return (unsigned short)((u + 0x7FFFu + ((u >> 16) & 1u)) >> 16);
}

// cW1 [K=1024][N=512] f32 row-major  ->  wT [N=512][K=1024] bf16
__global__ __launch_bounds__(256) void prep_transpose(const float* __restrict__ cW1,
                                                      unsigned short* __restrict__ wT) {
    __shared__ float tile[64][68];
    const int kt = blockIdx.x >> 3;
    const int nt = blockIdx.x & 7;
    const int tr = threadIdx.x >> 4;
    const int tc = threadIdx.x & 15;
#pragma unroll
    for (int i = 0; i < 4; ++i) {
        const f4 v = *(const f4*)(cW1 + (size_t)(kt * 64 + i * 16 + tr) * D_DIM + nt * 64 + tc * 4);
        tile[i * 16 + tr][tc * 4 + 0] = v.x;
        tile[i * 16 + tr][tc * 4 + 1] = v.y;
        tile[i * 16 + tr][tc * 4 + 2] = v.z;
        tile[i * 16 + tr][tc * 4 + 3] = v.w;
    }
    __syncthreads();
#pragma unroll
    for (int i = 0; i < 4; ++i) {
        const int n = i * 16 + tr;
        ushort4 o;
        o.x = f2bf(tile[tc * 4 + 0][n]);
        o.y = f2bf(tile[tc * 4 + 1][n]);
        o.z = f2bf(tile[tc * 4 + 2][n]);
        o.w = f2bf(tile[tc * 4 + 3][n]);
        *(ushort4*)(wT + (size_t)(nt * 64 + n) * H_DIM + kt * 64 + tc * 4) = o;
    }
}

// steps_used ≡ 1 (rb<=128-t can never make trunc(rb/(S-t+1))>=2; negative rb clips to 1),
// rb_final = 128 - 4096 = -3968.
__global__ __launch_bounds__(256) void write_consts(float* __restrict__ out) {
    const size_t steps_off = (size_t)B_DIM * S_LEN * H_DIM;
    const int i = blockIdx.x * 256 + threadIdx.x;
    if (i < S_LEN) out[steps_off + i] = 1.0f;
    if (i == 0) out[steps_off + 2 * S_LEN] = -3968.0f;
}

// HBM-bound fused stream: states copy -> d_out + comp_mean.
// Tile 64 rows (4 s x 16 b) x N=512, BK=64 (16 chunks). A and B BOTH double-buffered.
// One raw s_barrier per chunk; counted s_waitcnt vmcnt(4) (never 0 in the loop):
// in flight across each barrier = 2 A-prefetch loads (ck+2) + 2 store-acks.
__global__ __launch_bounds__(512, 2) void fused_gemm_kernel(
    const float* __restrict__ states,
    const unsigned short* __restrict__ wT,
    const float* __restrict__ cb1,
    const float* __restrict__ cW2,
    const float* __restrict__ cb2,
    float* __restrict__ out) {
    __shared__ unsigned short As[2][64][64];    // 16 KB, XOR-swizzled
    __shared__ unsigned short Bs[2][512][64];   // 128 KB, XOR-swizzled; total 144 KB -> 1 block/CU

    const int t = threadIdx.x;
    const int lane = t & 63;
    const int wv = t >> 6;        // 0..7 : wave col slice [wv*64, +64)
    const int la = lane & 15;
    const int lg = lane >> 4;
    const int s0 = blockIdx.x * 4;

    unsigned short* AsF = &As[0][0][0];
    unsigned short* BsF = &Bs[0][0][0];

    // ---- A staging map: 512 threads x 2 float4 = 64 rows x 64 k per chunk ----
    const int quad = t & 15;
    const int row0 = t >> 4;       // 0..31
    const int row1 = row0 + 32;    // 32..63
    const size_t g0 = ((size_t)(row0 & 15) * S_LEN + s0 + (row0 >> 4)) * H_DIM + quad * 4;
    const size_t g1 = ((size_t)(row1 & 15) * S_LEN + s0 + (row1 >> 4)) * H_DIM + quad * 4;
    const int lw0 = row0 * 64 + (((quad >> 1) ^ (row0 & 7)) * 8) + (quad & 1) * 4;
    const int lw1 = row1 * 64 + (((quad >> 1) ^ (row1 & 7)) * 8) + (quad & 1) * 4;

    // ---- B staging map: 8 global_load_lds(16B/lane) per wave per chunk ----
    const int srcslot = (lane & 7) ^ (lane >> 3);       // pre-swizzled source slot
    const unsigned short* bsrc = wT + (size_t)(wv * 8 + (lane >> 3)) * H_DIM + srcslot * 8;

    f4 acc[4][4];
#pragma unroll
    for (int a = 0; a < 4; ++a)
#pragma unroll
        for (int b = 0; b < 4; ++b) acc[a][b] = f4{0.f, 0.f, 0.f, 0.f};

    auto issueB = [&](int nb, int ck) {
#pragma unroll
        for (int i = 0; i < 8; ++i) {
            __builtin_amdgcn_global_load_lds(
                (gvp)(bsrc + (size_t)i * 64 * H_DIM + ck * 64),
                (lvp)(BsF + nb * 32768 + (i * 8 + wv) * 512),
                16, 0, 0);
        }
    };

    auto writeA = [&](int nb, int co, const f4 a0, const f4 a1) {
        __builtin_nontemporal_store(a0, (f4*)(out + g0 + co));   // fused states copy-out
        __builtin_nontemporal_store(a1, (f4*)(out + g1 + co));
        ushort4 p0; p0.x = f2bf(a0.x); p0.y = f2bf(a0.y); p0.z = f2bf(a0.z); p0.w = f2bf(a0.w);
        ushort4 p1; p1.x = f2bf(a1.x); p1.y = f2bf(a1.y); p1.z = f2bf(a1.z); p1.w = f2bf(a1.w);
        *(ushort4*)(AsF + nb * 4096 + lw0) = p0;
        *(ushort4*)(AsF + nb * 4096 + lw1) = p1;
    };

    auto compute = [&](int cb) {
#pragma unroll
        for (int kk = 0; kk < 2; ++kk) {
            const int sb = ((kk * 4 + lg) ^ (la & 7)) * 8;  // swizzled k-slot (row&7 == la&7)
            bf8 bfv[4], af[4];
#pragma unroll
            for (int fc = 0; fc < 4; ++fc)
                bfv[fc] = *(const bf8*)(BsF + cb * 32768 + (wv * 64 + fc * 16 + la) * 64 + sb);
#pragma unroll
            for (int fr = 0; fr < 4; ++fr)
                af[fr] = *(const bf8*)(AsF + cb * 4096 + (fr * 16 + la) * 64 + sb);
#pragma unroll
            for (int fr = 0; fr < 4; ++fr)
#pragma unroll
                for (int fc = 0; fc < 4; ++fc)
                    acc[fr][fc] = __builtin_amdgcn_mfma_f32_16x16x32_bf16(af[fr], bfv[fc], acc[fr][fc], 0, 0, 0);
        }
    };

    // ---- prologue: B(0)->Bs[0]; A(0) staged; A(1) in regs ----
    issueB(0, 0);
    f4 c0 = *(const f4*)(states + g0);
    f4 c1 = *(const f4*)(states + g1);
    f4 n0 = *(const f4*)(states + g0 + 64);
    f4 n1 = *(const f4*)(states + g1 + 64);
    writeA(0, 0, c0, c1);
    asm volatile("s_waitcnt vmcnt(4) lgkmcnt(0)" ::: "memory");
    __builtin_amdgcn_sched_barrier(0);
    __builtin_amdgcn_s_barrier();
    __builtin_amdgcn_sched_barrier(0);
    c0 = n0; c1 = n1;

    for (int ck = 0; ck < 16; ++ck) {
        const int cur = ck & 1;
        const int nb = cur ^ 1;
        issueB(nb, (ck < 15) ? ck + 1 : 15);             // B(ck+1) -> other buffer
        const int pf = ((ck < 14) ? ck + 2 : 15) * 64;   // A(ck+2) prefetch (clamped, uniform)
        n0 = *(const f4*)(states + g0 + pf);
        n1 = *(const f4*)(states + g1 + pf);
        compute(cur);
        writeA(nb, ((ck < 15) ? ck + 1 : 15) * 64, c0, c1);  // pack+ds_write+nt-store A(ck+1)
        asm volatile("s_waitcnt vmcnt(4) lgkmcnt(0)" ::: "memory");
        __builtin_amdgcn_sched_barrier(0);
        __builtin_amdgcn_s_barrier();
        __builtin_amdgcn_sched_barrier(0);
        c0 = n0; c1 = n1;
    }

    // ---- epilogue: relu + dot(cW2) + sigmoid + mean over b ----
    float w2v[4], b1v[4];
#pragma unroll
    for (int fc = 0; fc < 4; ++fc) {
        const int d = wv * 64 + fc * 16 + la;
        w2v[fc] = cW2[d];
        b1v[fc] = cb1[d];
    }
    float (*part)[16][8] = (float (*)[16][8])AsF;  // overlay on As[0] (last compute read As/Bs[1])
#pragma unroll
    for (int fr = 0; fr < 4; ++fr) {     // fr == s-offset j
#pragma unroll
        for (int rg = 0; rg < 4; ++rg) {
            float p = 0.f;
#pragma unroll
            for (int fc = 0; fc < 4; ++fc)
                p += fmaxf(acc[fr][fc][rg] + b1v[fc], 0.f) * w2v[fc];
#pragma unroll
            for (int off = 1; off < 16; off <<= 1)
                p += __shfl_xor(p, off, 64);   // sum over 16 lane-columns
            if (la == 0) part[fr][lg * 4 + rg][wv] = p;
        }
    }
    __syncthreads();
    if (t < 64) {
        const int j = t >> 4;   // s offset 0..3
        const int b = t & 15;
        float sum = cb2[0];
#pragma unroll
        for (int ww = 0; ww < 8; ++ww) sum += part[j][b][ww];
        float sg = 1.f / (1.f + __expf(-sum));
#pragma unroll
        for (int off = 1; off < 16; off <<= 1)
            sg += __shfl_xor(sg, off, 64);  // mean over b
        if (b == 0)
            out[(size_t)B_DIM * S_LEN * H_DIM + S_LEN + s0 + j] = sg * (1.f / 16.f);
    }
}

extern "C" void kernel_launch(void* const* d_in, const int* in_sizes, int n_in,
                              void* d_out, int out_size, void* d_ws, size_t ws_size,
                              hipStream_t stream) {
    const float* states = (const float*)d_in[0];
    const float* cW1 = (const float*)d_in[5];
    const float* cb1 = (const float*)d_in[6];
    const float* cW2 = (const float*)d_in[7];
    const float* cb2 = (const float*)d_in[8];
    float* out = (float*)d_out;
    unsigned short* wT = (unsigned short*)d_ws;  // 512x1024 bf16 = 1 MB

    hipLaunchKernelGGL(prep_transpose, dim3(128), dim3(256), 0, stream, cW1, wT);
    hipLaunchKernelGGL(write_consts, dim3(16), dim3(256), 0, stream, out);
    hipLaunchKernelGGL(fused_gemm_kernel, dim3(1024), dim3(512), 0, stream,
                       states, wT, cb1, cW2, cb2, out);
}